// Round 11
// baseline (32.526 us; speedup 1.0000x reference)
//
#include <hip/hip_runtime.h>
#include <hip/hip_fp16.h>

// Problem constants
#define BB 512      // batch
#define FF 1024     // features (= K of GEMM, = NK*KD)
#define NK 64       // num kernels
#define KD 16       // kernel dim

typedef __attribute__((ext_vector_type(4))) float f32x4;
typedef __attribute__((ext_vector_type(8))) _Float16 half8;
typedef __attribute__((ext_vector_type(8))) unsigned short ushort8;

__device__ __forceinline__ unsigned short f16_bits(float f) {
    __half h = __float2half(f);   // RNE
    return *reinterpret_cast<unsigned short*>(&h);
}

// ---------------------------------------------------------------------------
// FUSED prep+GEMM (R10-verified, out-zeroing removed): f32 x,T -> in-reg f16
// -> swizzled LDS -> MFMA. BM=32,BN=32,BK=64; 512 blocks, 256 thr, dbuf.
// Output M2[kblk][512][16] f32, kblk produced on XCD kblk>>3.
// ---------------------------------------------------------------------------
__global__ __launch_bounds__(256) void md_mfma_fused_kernel(
    const float* __restrict__ x, const float* __restrict__ T,
    float* __restrict__ M2) {
    __shared__ __align__(16) unsigned short lds[2][4096];

    const int t = threadIdx.x, w = t >> 6, l = t & 63;
    const int b = blockIdx.x, xc = b & 7, r = b >> 3;
    const int nt = xc * 4 + (r & 3);           // 0..31 (32-col n-tile)
    const int mt = r >> 2;                     // 0..15 (32-row m-tile)

    const int rowA = t >> 3, k8 = t & 7;
    const float* gA = x + (size_t)(mt * 32 + rowA) * FF + k8 * 8;
    const int wA = rowA * 64 + ((k8 ^ (rowA & 7)) * 8);   // swizzled ushort idx

    const int k2 = (t >> 3) * 2, nB = (t & 7) * 4;
    const float* gB = T + (size_t)k2 * FF + nt * 32 + nB;
    const int c16B = ((k2 >> 3) * 8);

    const int lrow = l & 15, lkg = l >> 4;
    const int ar = (w >> 1) * 16 + lrow;       // A row 0..31
    const int br = (w & 1) * 16 + lrow;        // B row 0..31
    const int swa = ar & 7, swb = br & 7;

    f32x4 acc = {};
    float4 a0[2], a1[2], b0[2], b1[2];

#define LOADT(s, it_) do {                                                  \
        a0[s] = *(const float4*)(gA + (it_) * 64);                          \
        a1[s] = *(const float4*)(gA + (it_) * 64 + 4);                      \
        b0[s] = *(const float4*)(gB + (size_t)(it_) * 64 * FF);             \
        b1[s] = *(const float4*)(gB + (size_t)(it_) * 64 * FF + FF);        \
    } while (0)

#define CVTW(s, bf) do {                                                    \
        ushort8 hv;                                                         \
        hv[0] = f16_bits(a0[s].x); hv[1] = f16_bits(a0[s].y);               \
        hv[2] = f16_bits(a0[s].z); hv[3] = f16_bits(a0[s].w);               \
        hv[4] = f16_bits(a1[s].x); hv[5] = f16_bits(a1[s].y);               \
        hv[6] = f16_bits(a1[s].z); hv[7] = f16_bits(a1[s].w);               \
        *(ushort8*)&lds[bf][wA] = hv;                                       \
        const float q0[4] = {b0[s].x, b0[s].y, b0[s].z, b0[s].w};           \
        const float q1[4] = {b1[s].x, b1[s].y, b1[s].z, b1[s].w};           \
        _Pragma("unroll")                                                   \
        for (int j = 0; j < 4; ++j) {                                       \
            const unsigned int pk = (unsigned int)f16_bits(q0[j]) |         \
                                    ((unsigned int)f16_bits(q1[j]) << 16);  \
            const int n = nB + j;                                           \
            *(unsigned int*)&lds[bf][2048 + n * 64 +                        \
                (c16B ^ ((n & 7) * 8)) + (k2 & 7)] = pk;                    \
        }                                                                   \
    } while (0)

    LOADT(0, 0);
    LOADT(1, 1);
    CVTW(0, 0);
    __syncthreads();

    #pragma unroll
    for (int it = 0; it < 16; ++it) {
        const int s = it & 1;
        if (it + 2 < 16) LOADT(s, it + 2);
        const unsigned short* L = lds[s];
        #pragma unroll
        for (int ks = 0; ks < 2; ++ks) {
            const int cb = ks * 4 + lkg;
            const half8 af = *(const half8*)&L[ar * 64 + ((cb ^ swa) * 8)];
            const half8 bf = *(const half8*)&L[2048 + br * 64 + ((cb ^ swb) * 8)];
            acc = __builtin_amdgcn_mfma_f32_16x16x32_f16(af, bf, acc, 0, 0, 0);
        }
        if (it + 1 < 16) {
            CVTW(s ^ 1, s ^ 1);
            __syncthreads();
        }
    }
#undef LOADT
#undef CVTW

    const int kblk = nt * 2 + (w & 1);           // 0..63
    const int rowb = mt * 32 + (w >> 1) * 16 + lkg * 4;
    #pragma unroll
    for (int rg = 0; rg < 4; ++rg)
        M2[((size_t)kblk * BB + rowb + rg) * KD + lrow] = acc[rg];
}

// ---------------------------------------------------------------------------
// Pairwise v2: NON-symmetric, SGPR-uniform mj, zero LDS/atomics in hot loop.
// Block = (i-tile of 64, k), XCD-matched to the GEMM's kblk producer.
// 512 blocks x 512 thr (8 waves); lane = i (mi[16] in VGPRs), wave wv owns
// j in [wv*64, wv*64+64). mj rows loaded via readfirstlane-uniformed
// addresses -> scalar path; inner loop = pure VALU (sub + |.|-add + exp).
// Final: 8-way partial reduce in LDS, direct store (out written once).
// ---------------------------------------------------------------------------
__global__ __launch_bounds__(512) void md_pairwise_kernel(
    const float* __restrict__ M2, float* __restrict__ out) {
    __shared__ float part[8][64];

    const int b = blockIdx.x;            // 512 = 8 xcd * 8 klo * 8 it
    const int xcd = b & 7, rest = b >> 3;
    const int k = xcd * 8 + (rest & 7);  // k's producer XCD == xcd
    const int it = rest >> 3;            // 0..7
    const int t = threadIdx.x, wv = t >> 6, i = t & 63;

    const float* col = M2 + (size_t)k * (BB * KD);   // [512][16] for this k

    // mi: lane's own row (it*64 + i); 64 lanes x 64B = 4KB contiguous
    float mi[16];
    {
        const float* mip = col + (size_t)(it * 64 + i) * KD;
        #pragma unroll
        for (int dg = 0; dg < 4; ++dg) {
            const float4 v = *(const float4*)(mip + dg * 4);
            mi[dg * 4 + 0] = v.x; mi[dg * 4 + 1] = v.y;
            mi[dg * 4 + 2] = v.z; mi[dg * 4 + 3] = v.w;
        }
    }

    float acc = 0.0f;
    const int j0 = wv * 64;
    #pragma unroll 2
    for (int jj = 0; jj < 64; ++jj) {
        // wave-uniform row offset -> scalar loads (no LDS, no per-lane VMEM)
        const int off = __builtin_amdgcn_readfirstlane((j0 + jj) * KD);
        const float4 v0 = *(const float4*)(col + off);
        const float4 v1 = *(const float4*)(col + off + 4);
        const float4 v2 = *(const float4*)(col + off + 8);
        const float4 v3 = *(const float4*)(col + off + 12);
        float p0 = (fabsf(mi[0] - v0.x) + fabsf(mi[1] - v0.y)) +
                   (fabsf(mi[2] - v0.z) + fabsf(mi[3] - v0.w));
        float p1 = (fabsf(mi[4] - v1.x) + fabsf(mi[5] - v1.y)) +
                   (fabsf(mi[6] - v1.z) + fabsf(mi[7] - v1.w));
        float p2 = (fabsf(mi[8] - v2.x) + fabsf(mi[9] - v2.y)) +
                   (fabsf(mi[10] - v2.z) + fabsf(mi[11] - v2.w));
        float p3 = (fabsf(mi[12] - v3.x) + fabsf(mi[13] - v3.y)) +
                   (fabsf(mi[14] - v3.z) + fabsf(mi[15] - v3.w));
        acc += __expf(-((p0 + p1) + (p2 + p3)));
    }

    part[wv][i] = acc;
    __syncthreads();
    if (t < 64) {
        const float s = ((part[0][t] + part[1][t]) + (part[2][t] + part[3][t])) +
                        ((part[4][t] + part[5][t]) + (part[6][t] + part[7][t])) - 1.0f;
        out[(size_t)(it * 64 + t) * NK + k] = s;   // written exactly once
    }
}

extern "C" void kernel_launch(void* const* d_in, const int* in_sizes, int n_in,
                              void* d_out, int out_size, void* d_ws, size_t ws_size,
                              hipStream_t stream) {
    const float* x = (const float*)d_in[0];   // [512, 1024] f32
    const float* T = (const float*)d_in[1];   // [1024, 1024] f32
    float* out = (float*)d_out;               // [512, 64] f32

    float* M2 = (float*)d_ws;                 // [64][512][16] f32 (2 MB)

    md_mfma_fused_kernel<<<dim3(512), 256, 0, stream>>>(x, T, M2);
    md_pairwise_kernel<<<dim3(512), 512, 0, stream>>>(M2, out);
}